// Round 4
// baseline (452.102 us; speedup 1.0000x reference)
//
#include <hip/hip_runtime.h>
#include <hip/hip_bf16.h>
#include <stdint.h>

#define M_DIM 4096
#define K_DIM 4096
#define N_DIM 11008
#define BKT 64                 // K per tile
#define NT (K_DIM / BKT)       // 64 k-tiles
#define GRID_MN 688            // (4096/256) * (11008/256) = 16*43
#define NBLK_M 16
#define NWG 256                // persistent workgroups (1 per CU)

typedef __attribute__((ext_vector_type(8))) short short8;
typedef __attribute__((ext_vector_type(4))) float floatx4;

// f32 -> bf16 round-to-nearest-even
__device__ __forceinline__ short f2bf(float f) {
  union { float f; uint32_t u; } c; c.f = f;
  uint32_t u = c.u;
  u += 0x7FFFu + ((u >> 16) & 1u);
  return (short)(u >> 16);
}

__device__ __forceinline__ void gload_lds16(const void* g, void* l) {
  __builtin_amdgcn_global_load_lds(
      (const __attribute__((address_space(1))) unsigned int*)g,
      (__attribute__((address_space(3))) unsigned int*)l, 16, 0, 0);
}

// ---------------- x: f32 -> bf16, plus exact f32 row sums ----------------
__global__ __launch_bounds__(256) void convert_x_kernel(const float* __restrict__ x,
                                                        short* __restrict__ xb,
                                                        float* __restrict__ rowsum) {
  const int m = blockIdx.x;
  const int t = threadIdx.x;
  const float* row = x + (size_t)m * K_DIM + t * 16;
  short* orow = xb + (size_t)m * K_DIM + t * 16;
  float4 v0 = *(const float4*)(row + 0);
  float4 v1 = *(const float4*)(row + 4);
  float4 v2 = *(const float4*)(row + 8);
  float4 v3 = *(const float4*)(row + 12);
  float sum = v0.x + v0.y + v0.z + v0.w
            + v1.x + v1.y + v1.z + v1.w
            + v2.x + v2.y + v2.z + v2.w
            + v3.x + v3.y + v3.z + v3.w;
  short8 o0, o1;
  o0[0] = f2bf(v0.x); o0[1] = f2bf(v0.y); o0[2] = f2bf(v0.z); o0[3] = f2bf(v0.w);
  o0[4] = f2bf(v1.x); o0[5] = f2bf(v1.y); o0[6] = f2bf(v1.z); o0[7] = f2bf(v1.w);
  o1[0] = f2bf(v2.x); o1[1] = f2bf(v2.y); o1[2] = f2bf(v2.z); o1[3] = f2bf(v2.w);
  o1[4] = f2bf(v3.x); o1[5] = f2bf(v3.y); o1[6] = f2bf(v3.z); o1[7] = f2bf(v3.w);
  *(short8*)(orow) = o0;
  *(short8*)(orow + 8) = o1;
  #pragma unroll
  for (int off = 32; off > 0; off >>= 1) sum += __shfl_down(sum, off);
  __shared__ float part[4];
  if ((t & 63) == 0) part[t >> 6] = sum;
  __syncthreads();
  if (t == 0) rowsum[m] = part[0] + part[1] + part[2] + part[3];
}

// ---------------- w: int32 [K][N] -> bf16 transposed [N][K] ----------------
__global__ __launch_bounds__(256) void convert_w_kernel(const int* __restrict__ w,
                                                        short* __restrict__ wt) {
  __shared__ short tile[64][72];
  const int bk = blockIdx.x * 64;
  const int bn = blockIdx.y * 64;
  const int t = threadIdx.x;
  const int kr = t >> 2;
  const int c0 = (t & 3) * 16;
  const int* src = w + (size_t)(bk + kr) * N_DIM + bn + c0;
  int4 a = *(const int4*)(src + 0);
  int4 b = *(const int4*)(src + 4);
  int4 c = *(const int4*)(src + 8);
  int4 d = *(const int4*)(src + 12);
  short* dst = &tile[kr][c0];
  dst[0]  = f2bf((float)a.x); dst[1]  = f2bf((float)a.y);
  dst[2]  = f2bf((float)a.z); dst[3]  = f2bf((float)a.w);
  dst[4]  = f2bf((float)b.x); dst[5]  = f2bf((float)b.y);
  dst[6]  = f2bf((float)b.z); dst[7]  = f2bf((float)b.w);
  dst[8]  = f2bf((float)c.x); dst[9]  = f2bf((float)c.y);
  dst[10] = f2bf((float)c.z); dst[11] = f2bf((float)c.w);
  dst[12] = f2bf((float)d.x); dst[13] = f2bf((float)d.y);
  dst[14] = f2bf((float)d.z); dst[15] = f2bf((float)d.w);
  __syncthreads();
  const int nr = t >> 2;
  short8 o0, o1;
  #pragma unroll
  for (int j = 0; j < 8; ++j) o0[j] = tile[c0 + j][nr];
  #pragma unroll
  for (int j = 0; j < 8; ++j) o1[j] = tile[c0 + 8 + j][nr];
  short* odst = wt + (size_t)(bn + nr) * K_DIM + bk + c0;
  *(short8*)(odst) = o0;
  *(short8*)(odst + 8) = o1;
}

// ---------------- main GEMM: persistent, 256x256 tile, 8 waves, 4-phase pipeline ----------------
// LDS: [buf][region: 0=A0,1=A1,2=B0,3=B1][128 rows x 64 k]
// Swizzle: 16B granule g of row stored at g ^ (row & 7).
// Per step s (buf beta=s&1): P1{read a03+b0 (12), MFMA Q00}  P2{read a47 (8),
// stage A1(s+1)->!beta, MFMA Q10}  P3{read b1 (4), stage A0(s+2)->beta, MFMA Q01}
// P4{stage B0,B1(s+2)->beta, vmcnt(6), MFMA Q11}.  Epilogue at kt==63 overlaps
// with already-issued next-tile loads.
__global__ __launch_bounds__(512, 2) void gemm_kernel(const short* __restrict__ xb,
                                                      const short* __restrict__ wt,
                                                      const float* __restrict__ scale,
                                                      const float* __restrict__ offset,
                                                      const float* __restrict__ rowsum,
                                                      float* __restrict__ out) {
  __shared__ short lds[2][4][8192];
  const int tid = threadIdx.x;
  // persistent + bijective XCD swizzle on 256 = 8*32
  const int w = blockIdx.x;
  const int swz0 = (w & 7) * 32 + (w >> 3);
  const int cnt = (swz0 < (GRID_MN - 2 * NWG)) ? 3 : 2;   // 688 = 2*256 + 176
  const int S = cnt * NT;

  int bmCur = (swz0 & 15) * 256;
  int bnCur = (swz0 >> 4) * 256;
  int TNext = swz0 + NWG;
  int bmNext = (TNext & 15) * 256;
  int bnNext = (TNext >> 4) * 256;

  const int wid = tid >> 6;
  const int lane = tid & 63;
  const int wr = wid >> 2;              // 0..1 : M half
  const int wc = wid & 3;               // 0..3 : N quarter
  const int hb = wc >> 1;               // which B half-region
  const int lr = lane & 15;
  const int lg = lane >> 4;
  const int swz = lr & 7;               // = row & 7 for every row this lane reads
  const int gk0 = (lg ^ swz) * 8;       // k-half 0 granule (shorts)
  const int gk1 = ((lg ^ 4) ^ swz) * 8; // k-half 1 granule (shorts)
  const int brow = (wc & 1) * 64 + lr;

  // staging: thread covers 16B slots tid and tid+512 of a 16KB half-tile
  const int srow = tid >> 3;                       // rows srow and srow+64
  const int glog = (tid & 7) ^ (srow & 7);         // logical granule for this slot

  auto stage = [&](const short* opbase, int rowbase, int half, int ktile, short* region) {
    const short* s0 = opbase + (size_t)(rowbase + half * 128 + srow) * K_DIM + ktile * BKT + glog * 8;
    gload_lds16(s0, (char*)region + tid * 16);
    const short* s1 = opbase + (size_t)(rowbase + half * 128 + srow + 64) * K_DIM + ktile * BKT + glog * 8;
    gload_lds16(s1, (char*)region + (tid + 512) * 16);
  };

  floatx4 acc[8][4];
  const floatx4 zero = {0.f, 0.f, 0.f, 0.f};
  #pragma unroll
  for (int i = 0; i < 8; ++i)
    #pragma unroll
    for (int j = 0; j < 4; ++j) acc[i][j] = zero;

  // ---- prologue: step0 {A0,A1,B0,B1} + step1 {A0,B0,B1} (A1(1) comes at s0.P2) ----
  stage(xb, bmCur, 0, 0, &lds[0][0][0]);
  stage(xb, bmCur, 1, 0, &lds[0][1][0]);
  stage(wt, bnCur, 0, 0, &lds[0][2][0]);
  stage(wt, bnCur, 1, 0, &lds[0][3][0]);
  stage(xb, bmCur, 0, 1, &lds[1][0][0]);
  stage(wt, bnCur, 0, 1, &lds[1][2][0]);
  stage(wt, bnCur, 1, 1, &lds[1][3][0]);
  asm volatile("s_waitcnt vmcnt(6)" ::: "memory");
  __builtin_amdgcn_s_barrier();

  for (int s = 0; s < S; ++s) {
    const int beta = s & 1;
    const int kt = s & 63;
    const short* As = &lds[beta][wr][0];
    const short* Bs = &lds[beta][2 + hb][0];
    short8 a03[4][2], a47[4][2], b0[2][2], b1[2][2];

    // ========== P1: read a03 (8) + b0 (4); MFMA Q00 ==========
    #pragma unroll
    for (int mf = 0; mf < 4; ++mf) {
      const short* p = As + (mf * 16 + lr) * 64;
      a03[mf][0] = *(const short8*)(p + gk0);
      a03[mf][1] = *(const short8*)(p + gk1);
    }
    #pragma unroll
    for (int nf = 0; nf < 2; ++nf) {
      const short* p = Bs + (brow + nf * 16) * 64;
      b0[nf][0] = *(const short8*)(p + gk0);
      b0[nf][1] = *(const short8*)(p + gk1);
    }
    asm volatile("s_waitcnt lgkmcnt(8)" ::: "memory");
    __builtin_amdgcn_s_barrier();
    asm volatile("s_waitcnt lgkmcnt(0)" ::: "memory");
    __builtin_amdgcn_s_setprio(1);
    #pragma unroll
    for (int mf = 0; mf < 4; ++mf)
      #pragma unroll
      for (int nf = 0; nf < 2; ++nf) {
        acc[mf][nf] = __builtin_amdgcn_mfma_f32_16x16x32_bf16(a03[mf][0], b0[nf][0], acc[mf][nf], 0, 0, 0);
        acc[mf][nf] = __builtin_amdgcn_mfma_f32_16x16x32_bf16(a03[mf][1], b0[nf][1], acc[mf][nf], 0, 0, 0);
      }
    __builtin_amdgcn_s_setprio(0);
    __builtin_amdgcn_s_barrier();

    // ========== P2: read a47 (8); stage A1(s+1) -> other buf; MFMA Q10 ==========
    #pragma unroll
    for (int mf = 0; mf < 4; ++mf) {
      const short* p = As + ((mf + 4) * 16 + lr) * 64;
      a47[mf][0] = *(const short8*)(p + gk0);
      a47[mf][1] = *(const short8*)(p + gk1);
    }
    {
      const int t1 = s + 1;
      if (t1 < S) {
        const int rb = ((t1 >> 6) != (s >> 6)) ? bmNext : bmCur;
        stage(xb, rb, 1, t1 & 63, &lds[beta ^ 1][1][0]);
      }
    }
    __builtin_amdgcn_s_barrier();
    asm volatile("s_waitcnt lgkmcnt(0)" ::: "memory");
    __builtin_amdgcn_s_setprio(1);
    #pragma unroll
    for (int mf = 0; mf < 4; ++mf)
      #pragma unroll
      for (int nf = 0; nf < 2; ++nf) {
        acc[mf + 4][nf] = __builtin_amdgcn_mfma_f32_16x16x32_bf16(a47[mf][0], b0[nf][0], acc[mf + 4][nf], 0, 0, 0);
        acc[mf + 4][nf] = __builtin_amdgcn_mfma_f32_16x16x32_bf16(a47[mf][1], b0[nf][1], acc[mf + 4][nf], 0, 0, 0);
      }
    __builtin_amdgcn_s_setprio(0);
    __builtin_amdgcn_s_barrier();

    // ========== P3: read b1 (4); stage A0(s+2) -> this buf; MFMA Q01 ==========
    #pragma unroll
    for (int nf = 0; nf < 2; ++nf) {
      const short* q = Bs + (brow + (nf + 2) * 16) * 64;
      b1[nf][0] = *(const short8*)(q + gk0);
      b1[nf][1] = *(const short8*)(q + gk1);
    }
    {
      const int t2 = s + 2;
      if (t2 < S) {
        const int rb = ((t2 >> 6) != (s >> 6)) ? bmNext : bmCur;
        stage(xb, rb, 0, t2 & 63, &lds[beta][0][0]);
      }
    }
    __builtin_amdgcn_s_barrier();
    asm volatile("s_waitcnt lgkmcnt(0)" ::: "memory");
    __builtin_amdgcn_s_setprio(1);
    #pragma unroll
    for (int mf = 0; mf < 4; ++mf)
      #pragma unroll
      for (int nf = 0; nf < 2; ++nf) {
        acc[mf][nf + 2] = __builtin_amdgcn_mfma_f32_16x16x32_bf16(a03[mf][0], b1[nf][0], acc[mf][nf + 2], 0, 0, 0);
        acc[mf][nf + 2] = __builtin_amdgcn_mfma_f32_16x16x32_bf16(a03[mf][1], b1[nf][1], acc[mf][nf + 2], 0, 0, 0);
      }
    __builtin_amdgcn_s_setprio(0);
    __builtin_amdgcn_s_barrier();

    // ========== P4: stage B0,B1(s+2) -> this buf; counted vmcnt; MFMA Q11 ==========
    {
      const int t2 = s + 2;
      if (t2 < S) {
        const int rb = ((t2 >> 6) != (s >> 6)) ? bnNext : bnCur;
        stage(wt, rb, 0, t2 & 63, &lds[beta][2][0]);
        stage(wt, rb, 1, t2 & 63, &lds[beta][3][0]);
        asm volatile("s_waitcnt vmcnt(6)" ::: "memory");
      } else {
        asm volatile("s_waitcnt vmcnt(0)" ::: "memory");
      }
    }
    __builtin_amdgcn_s_barrier();
    asm volatile("s_waitcnt lgkmcnt(0)" ::: "memory");
    __builtin_amdgcn_s_setprio(1);
    #pragma unroll
    for (int mf = 0; mf < 4; ++mf)
      #pragma unroll
      for (int nf = 0; nf < 2; ++nf) {
        acc[mf + 4][nf + 2] = __builtin_amdgcn_mfma_f32_16x16x32_bf16(a47[mf][0], b1[nf][0], acc[mf + 4][nf + 2], 0, 0, 0);
        acc[mf + 4][nf + 2] = __builtin_amdgcn_mfma_f32_16x16x32_bf16(a47[mf][1], b1[nf][1], acc[mf + 4][nf + 2], 0, 0, 0);
      }
    __builtin_amdgcn_s_setprio(0);
    __builtin_amdgcn_s_barrier();

    // ---- tile finished: epilogue (overlaps already-issued next-tile loads) ----
    if (kt == 63) {
      const int orow0 = bmCur + wr * 128 + lg * 4;
      const int ocol0 = bnCur + wc * 64 + lr;
      float4 rsv[8];
      #pragma unroll
      for (int amf = 0; amf < 8; ++amf)
        rsv[amf] = *(const float4*)&rowsum[orow0 + amf * 16];
      #pragma unroll
      for (int anf = 0; anf < 4; ++anf) {
        const int n = ocol0 + anf * 16;
        const float sc = scale[n];
        const float of = offset[n];
        #pragma unroll
        for (int amf = 0; amf < 8; ++amf) {
          const int mbase = orow0 + amf * 16;
          const float4 rv = rsv[amf];
          out[(size_t)(mbase + 0) * N_DIM + n] = (acc[amf][anf][0] + of * rv.x) * sc;
          out[(size_t)(mbase + 1) * N_DIM + n] = (acc[amf][anf][1] + of * rv.y) * sc;
          out[(size_t)(mbase + 2) * N_DIM + n] = (acc[amf][anf][2] + of * rv.z) * sc;
          out[(size_t)(mbase + 3) * N_DIM + n] = (acc[amf][anf][3] + of * rv.w) * sc;
        }
      }
      #pragma unroll
      for (int i = 0; i < 8; ++i)
        #pragma unroll
        for (int j = 0; j < 4; ++j) acc[i][j] = zero;
      bmCur = bmNext; bnCur = bnNext;
      TNext += NWG;
      bmNext = (TNext & 15) * 256;
      bnNext = (TNext >> 4) * 256;
    }
  }
}

// ---------------- fallback (ws too small): exact f32 tiled GEMM ----------------
__global__ __launch_bounds__(256) void fallback_gemm(const float* __restrict__ x,
                                                     const int* __restrict__ w,
                                                     const float* __restrict__ scale,
                                                     const float* __restrict__ offset,
                                                     float* __restrict__ out) {
  __shared__ float xs[32][33];
  __shared__ float bs[32][33];
  const int bm = blockIdx.y * 32, bn = blockIdx.x * 32;
  const int t = threadIdx.x;
  const int tm = t >> 5, tn = t & 31;
  float acc[4] = {0.f, 0.f, 0.f, 0.f};
  for (int k0 = 0; k0 < K_DIM; k0 += 32) {
    #pragma unroll
    for (int i = 0; i < 4; ++i) {
      int idx = t + i * 256; int r = idx >> 5, c = idx & 31;
      xs[r][c] = x[(size_t)(bm + r) * K_DIM + k0 + c];
      bs[r][c] = ((float)w[(size_t)(k0 + r) * N_DIM + bn + c] + offset[bn + c]) * scale[bn + c];
    }
    __syncthreads();
    #pragma unroll 8
    for (int kk = 0; kk < 32; ++kk) {
      float wv = bs[kk][tn];
      #pragma unroll
      for (int i = 0; i < 4; ++i) acc[i] += xs[tm + 8 * i][kk] * wv;
    }
    __syncthreads();
  }
  #pragma unroll
  for (int i = 0; i < 4; ++i)
    out[(size_t)(bm + tm + 8 * i) * N_DIM + bn + tn] = acc[i];
}

extern "C" void kernel_launch(void* const* d_in, const int* in_sizes, int n_in,
                              void* d_out, int out_size, void* d_ws, size_t ws_size,
                              hipStream_t stream) {
  const float* x      = (const float*)d_in[0];
  const int*   w      = (const int*)d_in[1];
  const float* scale  = (const float*)d_in[2];
  const float* offset = (const float*)d_in[3];
  float* out = (float*)d_out;

  const size_t xb_bytes = (size_t)M_DIM * K_DIM * 2;
  const size_t wt_bytes = (size_t)N_DIM * K_DIM * 2;
  const size_t rs_bytes = (size_t)M_DIM * 4;

  if (ws_size >= xb_bytes + wt_bytes + rs_bytes) {
    short* xb = (short*)d_ws;
    short* wt = (short*)((char*)d_ws + xb_bytes);
    float* rowsum = (float*)((char*)d_ws + xb_bytes + wt_bytes);
    convert_x_kernel<<<M_DIM, 256, 0, stream>>>(x, xb, rowsum);
    convert_w_kernel<<<dim3(K_DIM / 64, N_DIM / 64), 256, 0, stream>>>(w, wt);
    gemm_kernel<<<NWG, 512, 0, stream>>>(xb, wt, scale, offset, rowsum, out);
  } else {
    fallback_gemm<<<dim3(N_DIM / 32, M_DIM / 32), 256, 0, stream>>>(x, w, scale, offset, out);
  }
}

// Round 6
// 423.552 us; speedup vs baseline: 1.0674x; 1.0674x over previous
//
#include <hip/hip_runtime.h>
#include <hip/hip_bf16.h>
#include <stdint.h>

#define M_DIM 4096
#define K_DIM 4096
#define N_DIM 11008
#define BKT 64                 // K per tile
#define NT (K_DIM / BKT)       // 64 k-tiles
#define GRID_MN 688            // (4096/256) * (11008/256) = 16*43
#define NBLK_M 16

typedef __attribute__((ext_vector_type(8))) short short8;
typedef __attribute__((ext_vector_type(4))) float floatx4;

// f32 -> bf16 round-to-nearest-even
__device__ __forceinline__ short f2bf(float f) {
  union { float f; uint32_t u; } c; c.f = f;
  uint32_t u = c.u;
  u += 0x7FFFu + ((u >> 16) & 1u);
  return (short)(u >> 16);
}

__device__ __forceinline__ void gload_lds16(const void* g, void* l) {
  __builtin_amdgcn_global_load_lds(
      (const __attribute__((address_space(1))) unsigned int*)g,
      (__attribute__((address_space(3))) unsigned int*)l, 16, 0, 0);
}

// ---------------- x: f32 -> bf16, plus exact f32 row sums ----------------
__global__ __launch_bounds__(256) void convert_x_kernel(const float* __restrict__ x,
                                                        short* __restrict__ xb,
                                                        float* __restrict__ rowsum) {
  const int m = blockIdx.x;
  const int t = threadIdx.x;
  const float* row = x + (size_t)m * K_DIM + t * 16;
  short* orow = xb + (size_t)m * K_DIM + t * 16;
  float4 v0 = *(const float4*)(row + 0);
  float4 v1 = *(const float4*)(row + 4);
  float4 v2 = *(const float4*)(row + 8);
  float4 v3 = *(const float4*)(row + 12);
  float sum = v0.x + v0.y + v0.z + v0.w
            + v1.x + v1.y + v1.z + v1.w
            + v2.x + v2.y + v2.z + v2.w
            + v3.x + v3.y + v3.z + v3.w;
  short8 o0, o1;
  o0[0] = f2bf(v0.x); o0[1] = f2bf(v0.y); o0[2] = f2bf(v0.z); o0[3] = f2bf(v0.w);
  o0[4] = f2bf(v1.x); o0[5] = f2bf(v1.y); o0[6] = f2bf(v1.z); o0[7] = f2bf(v1.w);
  o1[0] = f2bf(v2.x); o1[1] = f2bf(v2.y); o1[2] = f2bf(v2.z); o1[3] = f2bf(v2.w);
  o1[4] = f2bf(v3.x); o1[5] = f2bf(v3.y); o1[6] = f2bf(v3.z); o1[7] = f2bf(v3.w);
  *(short8*)(orow) = o0;
  *(short8*)(orow + 8) = o1;
  #pragma unroll
  for (int off = 32; off > 0; off >>= 1) sum += __shfl_down(sum, off);
  __shared__ float part[4];
  if ((t & 63) == 0) part[t >> 6] = sum;
  __syncthreads();
  if (t == 0) rowsum[m] = part[0] + part[1] + part[2] + part[3];
}

// ---------------- w: int32 [K][N] -> bf16 transposed [N][K] ----------------
__global__ __launch_bounds__(256) void convert_w_kernel(const int* __restrict__ w,
                                                        short* __restrict__ wt) {
  __shared__ short tile[64][72];
  const int bk = blockIdx.x * 64;
  const int bn = blockIdx.y * 64;
  const int t = threadIdx.x;
  const int kr = t >> 2;
  const int c0 = (t & 3) * 16;
  const int* src = w + (size_t)(bk + kr) * N_DIM + bn + c0;
  int4 a = *(const int4*)(src + 0);
  int4 b = *(const int4*)(src + 4);
  int4 c = *(const int4*)(src + 8);
  int4 d = *(const int4*)(src + 12);
  short* dst = &tile[kr][c0];
  dst[0]  = f2bf((float)a.x); dst[1]  = f2bf((float)a.y);
  dst[2]  = f2bf((float)a.z); dst[3]  = f2bf((float)a.w);
  dst[4]  = f2bf((float)b.x); dst[5]  = f2bf((float)b.y);
  dst[6]  = f2bf((float)b.z); dst[7]  = f2bf((float)b.w);
  dst[8]  = f2bf((float)c.x); dst[9]  = f2bf((float)c.y);
  dst[10] = f2bf((float)c.z); dst[11] = f2bf((float)c.w);
  dst[12] = f2bf((float)d.x); dst[13] = f2bf((float)d.y);
  dst[14] = f2bf((float)d.z); dst[15] = f2bf((float)d.w);
  __syncthreads();
  const int nr = t >> 2;
  short8 o0, o1;
  #pragma unroll
  for (int j = 0; j < 8; ++j) o0[j] = tile[c0 + j][nr];
  #pragma unroll
  for (int j = 0; j < 8; ++j) o1[j] = tile[c0 + 8 + j][nr];
  short* odst = wt + (size_t)(bn + nr) * K_DIM + bk + c0;
  *(short8*)(odst) = o0;
  *(short8*)(odst + 8) = o1;
}

// ---------------- main GEMM: 256x256 tile, 8 waves, 4-phase pipeline ----------------
// LDS: [buf][region: 0=A0,1=A1,2=B0,3=B1][128 rows x 64 k]
// Swizzle: 16B granule g of row stored at g ^ (row & 7).
// Step s (buf b=s&1):
//   P1{read b0+b1 (8); lgkm(8); stage A1(s+1)->!b; Q00}
//   P2{read a47 (8);   stage B0(s+2)->b;           Q10}
//   P3{                stage A0(s+2)->b;           Q01}
//   P4{stage B1(s+2)->b; vmcnt(6); bar; PREFETCH a03(s+1) from !b (no wait); Q11}
// Reads 8/8/0/8, stages 2/2/2/2.  Safety invariants:
//  - all reads of a region complete (lgkm(0)+barrier) before its stage issues;
//  - vmcnt(6) at P4 retires exactly {A1,B0,A0,B1}(s+1) -> prefetch RAW-safe;
//  - lgkm(8) at P1 retires the prefetch reads before A1's region is re-staged.
__global__ __launch_bounds__(512, 2) void gemm_kernel(const short* __restrict__ xb,
                                                      const short* __restrict__ wt,
                                                      const float* __restrict__ scale,
                                                      const float* __restrict__ offset,
                                                      const float* __restrict__ rowsum,
                                                      float* __restrict__ out) {
  __shared__ short lds[2][4][8192];
  const int tid = threadIdx.x;
  // bijective XCD swizzle: 688 = 8 * 86; n-major so each XCD owns an N-slice
  const int bid = blockIdx.x;
  const int wg = (bid & 7) * (GRID_MN / 8) + (bid >> 3);
  const int bm = (wg % NBLK_M) * 256;
  const int bn = (wg / NBLK_M) * 256;

  const int wid = tid >> 6;
  const int lane = tid & 63;
  const int wr = wid >> 2;              // 0..1 : M half
  const int wc = wid & 3;               // 0..3 : N quarter
  const int hb = wc >> 1;               // which B half-region
  const int lr = lane & 15;
  const int lg = lane >> 4;
  const int swz = lr & 7;               // = row & 7 for every row this lane reads
  const int gk0 = (lg ^ swz) * 8;       // k-half 0 granule (shorts)
  const int gk1 = ((lg ^ 4) ^ swz) * 8; // k-half 1 granule (shorts)
  const int brow = (wc & 1) * 64 + lr;

  // staging: thread covers 16B slots tid and tid+512 of a 16KB half-tile
  const int srow = tid >> 3;                       // rows srow and srow+64
  const int glog = (tid & 7) ^ (srow & 7);         // logical granule for this slot

  auto stage = [&](const short* opbase, int rowbase, int half, int kt, short* region) {
    const short* s0 = opbase + (size_t)(rowbase + half * 128 + srow) * K_DIM + kt * BKT + glog * 8;
    gload_lds16(s0, (char*)region + tid * 16);
    const short* s1 = opbase + (size_t)(rowbase + half * 128 + srow + 64) * K_DIM + kt * BKT + glog * 8;
    gload_lds16(s1, (char*)region + (tid + 512) * 16);
  };

  floatx4 acc[8][4];
  const floatx4 zero = {0.f, 0.f, 0.f, 0.f};
  #pragma unroll
  for (int i = 0; i < 8; ++i)
    #pragma unroll
    for (int j = 0; j < 4; ++j) acc[i][j] = zero;

  // ---- prologue: tile0 {A0,A1,B0,B1}, then B0(1),A0(1),B1(1); A1(1) at s0.P1 ----
  stage(xb, bm, 0, 0, &lds[0][0][0]);
  stage(xb, bm, 1, 0, &lds[0][1][0]);
  stage(wt, bn, 0, 0, &lds[0][2][0]);
  stage(wt, bn, 1, 0, &lds[0][3][0]);
  stage(wt, bn, 0, 1, &lds[1][2][0]);
  stage(xb, bm, 0, 1, &lds[1][0][0]);
  stage(wt, bn, 1, 1, &lds[1][3][0]);
  asm volatile("s_waitcnt vmcnt(6)" ::: "memory");
  __builtin_amdgcn_s_barrier();

  short8 a03[4][2], a47[4][2], b0[2][2], b1[2][2];
  {
    const short* As = &lds[0][wr][0];
    #pragma unroll
    for (int mf = 0; mf < 4; ++mf) {
      const short* p = As + (mf * 16 + lr) * 64;
      a03[mf][0] = *(const short8*)(p + gk0);
      a03[mf][1] = *(const short8*)(p + gk1);
    }
  }

  for (int s = 0; s < NT; ++s) {
    const int beta = s & 1;
    const short* As = &lds[beta][wr][0];
    const short* Bs = &lds[beta][2 + hb][0];

    // ========== P1: read b0+b1 (8); lgkm(8); stage A1(s+1)->!beta; Q00 ==========
    #pragma unroll
    for (int nf = 0; nf < 2; ++nf) {
      const short* p = Bs + (brow + nf * 16) * 64;
      b0[nf][0] = *(const short8*)(p + gk0);
      b0[nf][1] = *(const short8*)(p + gk1);
      const short* q = Bs + (brow + (nf + 2) * 16) * 64;
      b1[nf][0] = *(const short8*)(q + gk0);
      b1[nf][1] = *(const short8*)(q + gk1);
    }
    asm volatile("s_waitcnt lgkmcnt(8)" ::: "memory");  // retire a03 prefetch before A1 restage
    if (s + 1 < NT) stage(xb, bm, 1, s + 1, &lds[beta ^ 1][1][0]);
    __builtin_amdgcn_s_barrier();
    asm volatile("s_waitcnt lgkmcnt(0)" ::: "memory");
    __builtin_amdgcn_s_setprio(1);
    #pragma unroll
    for (int mf = 0; mf < 4; ++mf)
      #pragma unroll
      for (int nf = 0; nf < 2; ++nf) {
        acc[mf][nf] = __builtin_amdgcn_mfma_f32_16x16x32_bf16(a03[mf][0], b0[nf][0], acc[mf][nf], 0, 0, 0);
        acc[mf][nf] = __builtin_amdgcn_mfma_f32_16x16x32_bf16(a03[mf][1], b0[nf][1], acc[mf][nf], 0, 0, 0);
      }
    __builtin_amdgcn_s_setprio(0);
    __builtin_amdgcn_s_barrier();

    // ========== P2: read a47 (8); stage B0(s+2)->this buf; Q10 ==========
    #pragma unroll
    for (int mf = 0; mf < 4; ++mf) {
      const short* p = As + ((mf + 4) * 16 + lr) * 64;
      a47[mf][0] = *(const short8*)(p + gk0);
      a47[mf][1] = *(const short8*)(p + gk1);
    }
    if (s + 2 < NT) stage(wt, bn, 0, s + 2, &lds[beta][2][0]);
    __builtin_amdgcn_s_barrier();
    asm volatile("s_waitcnt lgkmcnt(0)" ::: "memory");
    __builtin_amdgcn_s_setprio(1);
    #pragma unroll
    for (int mf = 0; mf < 4; ++mf)
      #pragma unroll
      for (int nf = 0; nf < 2; ++nf) {
        acc[mf + 4][nf] = __builtin_amdgcn_mfma_f32_16x16x32_bf16(a47[mf][0], b0[nf][0], acc[mf + 4][nf], 0, 0, 0);
        acc[mf + 4][nf] = __builtin_amdgcn_mfma_f32_16x16x32_bf16(a47[mf][1], b0[nf][1], acc[mf + 4][nf], 0, 0, 0);
      }
    __builtin_amdgcn_s_setprio(0);
    __builtin_amdgcn_s_barrier();

    // ========== P3: stage A0(s+2)->this buf; Q01 (operands in regs) ==========
    if (s + 2 < NT) stage(xb, bm, 0, s + 2, &lds[beta][0][0]);
    __builtin_amdgcn_s_barrier();
    __builtin_amdgcn_s_setprio(1);
    #pragma unroll
    for (int mf = 0; mf < 4; ++mf)
      #pragma unroll
      for (int nf = 0; nf < 2; ++nf) {
        acc[mf][nf + 2] = __builtin_amdgcn_mfma_f32_16x16x32_bf16(a03[mf][0], b1[nf][0], acc[mf][nf + 2], 0, 0, 0);
        acc[mf][nf + 2] = __builtin_amdgcn_mfma_f32_16x16x32_bf16(a03[mf][1], b1[nf][1], acc[mf][nf + 2], 0, 0, 0);
      }
    __builtin_amdgcn_s_setprio(0);
    __builtin_amdgcn_s_barrier();

    // ========== P4: stage B1(s+2); vmcnt(6); prefetch a03(s+1); Q11 ==========
    if (s + 2 < NT) {
      stage(wt, bn, 1, s + 2, &lds[beta][3][0]);
      asm volatile("s_waitcnt vmcnt(6)" ::: "memory");
    } else {
      asm volatile("s_waitcnt vmcnt(0)" ::: "memory");
    }
    __builtin_amdgcn_s_barrier();
    if (s + 1 < NT) {
      const short* An = &lds[beta ^ 1][wr][0];
      #pragma unroll
      for (int mf = 0; mf < 4; ++mf) {
        const short* p = An + (mf * 16 + lr) * 64;
        a03[mf][0] = *(const short8*)(p + gk0);
        a03[mf][1] = *(const short8*)(p + gk1);
      }
    }
    // no lgkm wait: Q11's operands (a47,b1) are in registers; the a03
    // prefetch completes in the background (next P1's lgkm(8)/lgkm(0) covers it).
    __builtin_amdgcn_s_setprio(1);
    #pragma unroll
    for (int mf = 0; mf < 4; ++mf)
      #pragma unroll
      for (int nf = 0; nf < 2; ++nf) {
        acc[mf + 4][nf + 2] = __builtin_amdgcn_mfma_f32_16x16x32_bf16(a47[mf][0], b1[nf][0], acc[mf + 4][nf + 2], 0, 0, 0);
        acc[mf + 4][nf + 2] = __builtin_amdgcn_mfma_f32_16x16x32_bf16(a47[mf][1], b1[nf][1], acc[mf + 4][nf + 2], 0, 0, 0);
      }
    __builtin_amdgcn_s_setprio(0);
    __builtin_amdgcn_s_barrier();
  }

  // ---- epilogue: out = (G + offset[n]*rowsum[m]) * scale[n] ----
  const int orow0 = bm + wr * 128 + lg * 4;
  const int ocol0 = bn + wc * 64 + lr;
  float4 rsv[8];
  #pragma unroll
  for (int amf = 0; amf < 8; ++amf)
    rsv[amf] = *(const float4*)&rowsum[orow0 + amf * 16];
  #pragma unroll
  for (int anf = 0; anf < 4; ++anf) {
    const int n = ocol0 + anf * 16;
    const float sc = scale[n];
    const float of = offset[n];
    #pragma unroll
    for (int amf = 0; amf < 8; ++amf) {
      const int mbase = orow0 + amf * 16;
      const float4 rv = rsv[amf];
      out[(size_t)(mbase + 0) * N_DIM + n] = (acc[amf][anf][0] + of * rv.x) * sc;
      out[(size_t)(mbase + 1) * N_DIM + n] = (acc[amf][anf][1] + of * rv.y) * sc;
      out[(size_t)(mbase + 2) * N_DIM + n] = (acc[amf][anf][2] + of * rv.z) * sc;
      out[(size_t)(mbase + 3) * N_DIM + n] = (acc[amf][anf][3] + of * rv.w) * sc;
    }
  }
}

// ---------------- fallback (ws too small): exact f32 tiled GEMM ----------------
__global__ __launch_bounds__(256) void fallback_gemm(const float* __restrict__ x,
                                                     const int* __restrict__ w,
                                                     const float* __restrict__ scale,
                                                     const float* __restrict__ offset,
                                                     float* __restrict__ out) {
  __shared__ float xs[32][33];
  __shared__ float bs[32][33];
  const int bm = blockIdx.y * 32, bn = blockIdx.x * 32;
  const int t = threadIdx.x;
  const int tm = t >> 5, tn = t & 31;
  float acc[4] = {0.f, 0.f, 0.f, 0.f};
  for (int k0 = 0; k0 < K_DIM; k0 += 32) {
    #pragma unroll
    for (int i = 0; i < 4; ++i) {
      int idx = t + i * 256; int r = idx >> 5, c = idx & 31;
      xs[r][c] = x[(size_t)(bm + r) * K_DIM + k0 + c];
      bs[r][c] = ((float)w[(size_t)(k0 + r) * N_DIM + bn + c] + offset[bn + c]) * scale[bn + c];
    }
    __syncthreads();
    #pragma unroll 8
    for (int kk = 0; kk < 32; ++kk) {
      float wv = bs[kk][tn];
      #pragma unroll
      for (int i = 0; i < 4; ++i) acc[i] += xs[tm + 8 * i][kk] * wv;
    }
    __syncthreads();
  }
  #pragma unroll
  for (int i = 0; i < 4; ++i)
    out[(size_t)(bm + tm + 8 * i) * N_DIM + bn + tn] = acc[i];
}

extern "C" void kernel_launch(void* const* d_in, const int* in_sizes, int n_in,
                              void* d_out, int out_size, void* d_ws, size_t ws_size,
                              hipStream_t stream) {
  const float* x      = (const float*)d_in[0];
  const int*   w      = (const int*)d_in[1];
  const float* scale  = (const float*)d_in[2];
  const float* offset = (const float*)d_in[3];
  float* out = (float*)d_out;

  const size_t xb_bytes = (size_t)M_DIM * K_DIM * 2;
  const size_t wt_bytes = (size_t)N_DIM * K_DIM * 2;
  const size_t rs_bytes = (size_t)M_DIM * 4;

  if (ws_size >= xb_bytes + wt_bytes + rs_bytes) {
    short* xb = (short*)d_ws;
    short* wt = (short*)((char*)d_ws + xb_bytes);
    float* rowsum = (float*)((char*)d_ws + xb_bytes + wt_bytes);
    convert_x_kernel<<<M_DIM, 256, 0, stream>>>(x, xb, rowsum);
    convert_w_kernel<<<dim3(K_DIM / 64, N_DIM / 64), 256, 0, stream>>>(w, wt);
    gemm_kernel<<<GRID_MN, 512, 0, stream>>>(xb, wt, scale, offset, rowsum, out);
  } else {
    fallback_gemm<<<dim3(N_DIM / 32, M_DIM / 32), 256, 0, stream>>>(x, w, scale, offset, out);
  }
}

// Round 7
// 404.918 us; speedup vs baseline: 1.1165x; 1.0460x over previous
//
#include <hip/hip_runtime.h>
#include <hip/hip_bf16.h>
#include <stdint.h>

#define M_DIM 4096
#define K_DIM 4096
#define N_DIM 11008
#define BKT 64                 // K per tile
#define NT (K_DIM / BKT)       // 64 k-tiles
#define GRID_MN 688            // (4096/256) * (11008/256) = 16*43
#define NBLK_M 16

typedef __attribute__((ext_vector_type(8))) short short8;
typedef __attribute__((ext_vector_type(4))) float floatx4;

// f32 -> bf16 round-to-nearest-even
__device__ __forceinline__ short f2bf(float f) {
  union { float f; uint32_t u; } c; c.f = f;
  uint32_t u = c.u;
  u += 0x7FFFu + ((u >> 16) & 1u);
  return (short)(u >> 16);
}

__device__ __forceinline__ void gload_lds16(const void* g, void* l) {
  __builtin_amdgcn_global_load_lds(
      (const __attribute__((address_space(1))) unsigned int*)g,
      (__attribute__((address_space(3))) unsigned int*)l, 16, 0, 0);
}

// ---------------- x: f32 -> bf16, plus exact f32 row sums ----------------
__global__ __launch_bounds__(256) void convert_x_kernel(const float* __restrict__ x,
                                                        short* __restrict__ xb,
                                                        float* __restrict__ rowsum) {
  const int m = blockIdx.x;
  const int t = threadIdx.x;
  const float* row = x + (size_t)m * K_DIM + t * 16;
  short* orow = xb + (size_t)m * K_DIM + t * 16;
  float4 v0 = *(const float4*)(row + 0);
  float4 v1 = *(const float4*)(row + 4);
  float4 v2 = *(const float4*)(row + 8);
  float4 v3 = *(const float4*)(row + 12);
  float sum = v0.x + v0.y + v0.z + v0.w
            + v1.x + v1.y + v1.z + v1.w
            + v2.x + v2.y + v2.z + v2.w
            + v3.x + v3.y + v3.z + v3.w;
  short8 o0, o1;
  o0[0] = f2bf(v0.x); o0[1] = f2bf(v0.y); o0[2] = f2bf(v0.z); o0[3] = f2bf(v0.w);
  o0[4] = f2bf(v1.x); o0[5] = f2bf(v1.y); o0[6] = f2bf(v1.z); o0[7] = f2bf(v1.w);
  o1[0] = f2bf(v2.x); o1[1] = f2bf(v2.y); o1[2] = f2bf(v2.z); o1[3] = f2bf(v2.w);
  o1[4] = f2bf(v3.x); o1[5] = f2bf(v3.y); o1[6] = f2bf(v3.z); o1[7] = f2bf(v3.w);
  *(short8*)(orow) = o0;
  *(short8*)(orow + 8) = o1;
  #pragma unroll
  for (int off = 32; off > 0; off >>= 1) sum += __shfl_down(sum, off);
  __shared__ float part[4];
  if ((t & 63) == 0) part[t >> 6] = sum;
  __syncthreads();
  if (t == 0) rowsum[m] = part[0] + part[1] + part[2] + part[3];
}

// ---------------- w: int32 [K][N] -> bf16 transposed [N][K] ----------------
__global__ __launch_bounds__(256) void convert_w_kernel(const int* __restrict__ w,
                                                        short* __restrict__ wt) {
  __shared__ short tile[64][72];
  const int bk = blockIdx.x * 64;
  const int bn = blockIdx.y * 64;
  const int t = threadIdx.x;
  const int kr = t >> 2;
  const int c0 = (t & 3) * 16;
  const int* src = w + (size_t)(bk + kr) * N_DIM + bn + c0;
  int4 a = *(const int4*)(src + 0);
  int4 b = *(const int4*)(src + 4);
  int4 c = *(const int4*)(src + 8);
  int4 d = *(const int4*)(src + 12);
  short* dst = &tile[kr][c0];
  dst[0]  = f2bf((float)a.x); dst[1]  = f2bf((float)a.y);
  dst[2]  = f2bf((float)a.z); dst[3]  = f2bf((float)a.w);
  dst[4]  = f2bf((float)b.x); dst[5]  = f2bf((float)b.y);
  dst[6]  = f2bf((float)b.z); dst[7]  = f2bf((float)b.w);
  dst[8]  = f2bf((float)c.x); dst[9]  = f2bf((float)c.y);
  dst[10] = f2bf((float)c.z); dst[11] = f2bf((float)c.w);
  dst[12] = f2bf((float)d.x); dst[13] = f2bf((float)d.y);
  dst[14] = f2bf((float)d.z); dst[15] = f2bf((float)d.w);
  __syncthreads();
  const int nr = t >> 2;
  short8 o0, o1;
  #pragma unroll
  for (int j = 0; j < 8; ++j) o0[j] = tile[c0 + j][nr];
  #pragma unroll
  for (int j = 0; j < 8; ++j) o1[j] = tile[c0 + 8 + j][nr];
  short* odst = wt + (size_t)(bn + nr) * K_DIM + bk + c0;
  *(short8*)(odst) = o0;
  *(short8*)(odst + 8) = o1;
}

// ---------------- main GEMM: 256x256 tile, 8 waves, JIT-refill pipeline ----------------
// LDS: [buf][region: 0=A0,1=A1,2=B0,3=B1][128 rows x 64 k]
// Swizzle: 16B granule g of row stored at g ^ (row & 7).
// Step u (buf g=u&1), 4 barriers/step, reads always 1 phase ahead of use:
//   P1{read a47(u); lgkm(8); BAR; stage A1(u+1)->!g;  Q00=a03*b0}
//   P2{read b1(u);  lgkm(4); BAR; stage A0(u+2)->g;   Q10=a47*b0}
//   P3{             lgkm(0); BAR; stage B0(u+2)->g;   Q01=a03*b1}
//   P4{stage B1(u+2)->g; vmcnt(6); BAR; read a03,b0(u+1) from !g; Q11=a47*b1}
// Safety: every stage issues only after a barrier that follows chip-wide
// retirement of all reads from its region (lgkm(8/4/0) are pre-barrier).
// vmcnt FIFO: 14 outstanding at P4's vmcnt(6) -> retires exactly tile u+1.
__global__ __launch_bounds__(512, 2) void gemm_kernel(const short* __restrict__ xb,
                                                      const short* __restrict__ wt,
                                                      const float* __restrict__ scale,
                                                      const float* __restrict__ offset,
                                                      const float* __restrict__ rowsum,
                                                      float* __restrict__ out) {
  __shared__ short lds[2][4][8192];
  const int tid = threadIdx.x;
  // bijective XCD swizzle: 688 = 8 * 86; n-major so each XCD owns an N-slice
  const int bid = blockIdx.x;
  const int wg = (bid & 7) * (GRID_MN / 8) + (bid >> 3);
  const int bm = (wg % NBLK_M) * 256;
  const int bn = (wg / NBLK_M) * 256;

  const int wid = tid >> 6;
  const int lane = tid & 63;
  const int wr = wid >> 2;              // 0..1 : M half
  const int wc = wid & 3;               // 0..3 : N quarter
  const int hb = wc >> 1;               // which B half-region
  const int lr = lane & 15;
  const int lg = lane >> 4;
  const int swz = lr & 7;               // = row & 7 for every row this lane reads
  const int gk0 = (lg ^ swz) * 8;       // k-half 0 granule (shorts)
  const int gk1 = ((lg ^ 4) ^ swz) * 8; // k-half 1 granule (shorts)
  const int brow = (wc & 1) * 64 + lr;

  // staging: thread covers 16B slots tid and tid+512 of a 16KB half-tile
  const int srow = tid >> 3;                       // rows srow and srow+64
  const int glog = (tid & 7) ^ (srow & 7);         // logical granule for this slot

  auto stage = [&](const short* opbase, int rowbase, int half, int kt, short* region) {
    const short* s0 = opbase + (size_t)(rowbase + half * 128 + srow) * K_DIM + kt * BKT + glog * 8;
    gload_lds16(s0, (char*)region + tid * 16);
    const short* s1 = opbase + (size_t)(rowbase + half * 128 + srow + 64) * K_DIM + kt * BKT + glog * 8;
    gload_lds16(s1, (char*)region + (tid + 512) * 16);
  };

  floatx4 acc[8][4];
  const floatx4 zero = {0.f, 0.f, 0.f, 0.f};
  #pragma unroll
  for (int i = 0; i < 8; ++i)
    #pragma unroll
    for (int j = 0; j < 4; ++j) acc[i][j] = zero;

  // ---- prologue ----
  stage(xb, bm, 0, 0, &lds[0][0][0]);
  stage(xb, bm, 1, 0, &lds[0][1][0]);
  stage(wt, bn, 0, 0, &lds[0][2][0]);
  stage(wt, bn, 1, 0, &lds[0][3][0]);
  asm volatile("s_waitcnt vmcnt(0)" ::: "memory");
  __builtin_amdgcn_s_barrier();

  short8 a03[4][2], a47[4][2], b0[2][2], b1[2][2];
  {
    // read a03(0), b0(0): 12 lgkm outstanding entering the loop
    const short* As = &lds[0][wr][0];
    #pragma unroll
    for (int mf = 0; mf < 4; ++mf) {
      const short* p = As + (mf * 16 + lr) * 64;
      a03[mf][0] = *(const short8*)(p + gk0);
      a03[mf][1] = *(const short8*)(p + gk1);
    }
    const short* Bsp = &lds[0][2 + hb][0];
    #pragma unroll
    for (int nf = 0; nf < 2; ++nf) {
      const short* p = Bsp + (brow + nf * 16) * 64;
      b0[nf][0] = *(const short8*)(p + gk0);
      b0[nf][1] = *(const short8*)(p + gk1);
    }
  }
  // stage tile1 {A0,B0,B1}: 6 vm outstanding entering the loop (A1(1) at P1(0))
  stage(xb, bm, 0, 1, &lds[1][0][0]);
  stage(wt, bn, 0, 1, &lds[1][2][0]);
  stage(wt, bn, 1, 1, &lds[1][3][0]);

  for (int u = 0; u < NT; ++u) {
    const int g = u & 1;
    const short* As = &lds[g][wr][0];
    const short* Bs = &lds[g][2 + hb][0];

    // ========== P1: read a47(u); lgkm(8); BAR; stage A1(u+1); Q00 ==========
    #pragma unroll
    for (int mf = 0; mf < 4; ++mf) {
      const short* p = As + ((mf + 4) * 16 + lr) * 64;
      a47[mf][0] = *(const short8*)(p + gk0);
      a47[mf][1] = *(const short8*)(p + gk1);
    }
    asm volatile("s_waitcnt lgkmcnt(8)" ::: "memory");  // a03,b0(u) retired
    __builtin_amdgcn_s_barrier();
    if (u + 1 < NT) stage(xb, bm, 1, u + 1, &lds[g ^ 1][1][0]);
    __builtin_amdgcn_s_setprio(1);
    #pragma unroll
    for (int mf = 0; mf < 4; ++mf)
      #pragma unroll
      for (int nf = 0; nf < 2; ++nf) {
        acc[mf][nf] = __builtin_amdgcn_mfma_f32_16x16x32_bf16(a03[mf][0], b0[nf][0], acc[mf][nf], 0, 0, 0);
        acc[mf][nf] = __builtin_amdgcn_mfma_f32_16x16x32_bf16(a03[mf][1], b0[nf][1], acc[mf][nf], 0, 0, 0);
      }
    __builtin_amdgcn_s_setprio(0);

    // ========== P2: read b1(u); lgkm(4); BAR; stage A0(u+2); Q10 ==========
    #pragma unroll
    for (int nf = 0; nf < 2; ++nf) {
      const short* q = Bs + (brow + (nf + 2) * 16) * 64;
      b1[nf][0] = *(const short8*)(q + gk0);
      b1[nf][1] = *(const short8*)(q + gk1);
    }
    asm volatile("s_waitcnt lgkmcnt(4)" ::: "memory");  // a47(u) retired
    __builtin_amdgcn_s_barrier();
    if (u + 2 < NT) stage(xb, bm, 0, u + 2, &lds[g][0][0]);
    __builtin_amdgcn_s_setprio(1);
    #pragma unroll
    for (int mf = 0; mf < 4; ++mf)
      #pragma unroll
      for (int nf = 0; nf < 2; ++nf) {
        acc[mf + 4][nf] = __builtin_amdgcn_mfma_f32_16x16x32_bf16(a47[mf][0], b0[nf][0], acc[mf + 4][nf], 0, 0, 0);
        acc[mf + 4][nf] = __builtin_amdgcn_mfma_f32_16x16x32_bf16(a47[mf][1], b0[nf][1], acc[mf + 4][nf], 0, 0, 0);
      }
    __builtin_amdgcn_s_setprio(0);

    // ========== P3: lgkm(0); BAR; stage B0(u+2); Q01 ==========
    asm volatile("s_waitcnt lgkmcnt(0)" ::: "memory");  // b1(u) retired
    __builtin_amdgcn_s_barrier();
    if (u + 2 < NT) stage(wt, bn, 0, u + 2, &lds[g][2][0]);
    __builtin_amdgcn_s_setprio(1);
    #pragma unroll
    for (int mf = 0; mf < 4; ++mf)
      #pragma unroll
      for (int nf = 0; nf < 2; ++nf) {
        acc[mf][nf + 2] = __builtin_amdgcn_mfma_f32_16x16x32_bf16(a03[mf][0], b1[nf][0], acc[mf][nf + 2], 0, 0, 0);
        acc[mf][nf + 2] = __builtin_amdgcn_mfma_f32_16x16x32_bf16(a03[mf][1], b1[nf][1], acc[mf][nf + 2], 0, 0, 0);
      }
    __builtin_amdgcn_s_setprio(0);

    // ========== P4: stage B1(u+2); vmcnt; BAR; read a03,b0(u+1); Q11 ==========
    if (u + 2 < NT) {
      stage(wt, bn, 1, u + 2, &lds[g][3][0]);
      asm volatile("s_waitcnt vmcnt(6)" ::: "memory");  // tile u+1 fully landed
    } else {
      asm volatile("s_waitcnt vmcnt(0)" ::: "memory");
    }
    __builtin_amdgcn_s_barrier();
    if (u + 1 < NT) {
      const short* An = &lds[g ^ 1][wr][0];
      const short* Bn = &lds[g ^ 1][2 + hb][0];
      #pragma unroll
      for (int mf = 0; mf < 4; ++mf) {
        const short* p = An + (mf * 16 + lr) * 64;
        a03[mf][0] = *(const short8*)(p + gk0);
        a03[mf][1] = *(const short8*)(p + gk1);
      }
      #pragma unroll
      for (int nf = 0; nf < 2; ++nf) {
        const short* p = Bn + (brow + nf * 16) * 64;
        b0[nf][0] = *(const short8*)(p + gk0);
        b0[nf][1] = *(const short8*)(p + gk1);
      }
    }
    __builtin_amdgcn_s_setprio(1);
    #pragma unroll
    for (int mf = 0; mf < 4; ++mf)
      #pragma unroll
      for (int nf = 0; nf < 2; ++nf) {
        acc[mf + 4][nf + 2] = __builtin_amdgcn_mfma_f32_16x16x32_bf16(a47[mf][0], b1[nf][0], acc[mf + 4][nf + 2], 0, 0, 0);
        acc[mf + 4][nf + 2] = __builtin_amdgcn_mfma_f32_16x16x32_bf16(a47[mf][1], b1[nf][1], acc[mf + 4][nf + 2], 0, 0, 0);
      }
    __builtin_amdgcn_s_setprio(0);
  }

  // ---- epilogue: out = (G + offset[n]*rowsum[m]) * scale[n] ----
  const int orow0 = bm + wr * 128 + lg * 4;
  const int ocol0 = bn + wc * 64 + lr;
  float4 rsv[8];
  #pragma unroll
  for (int amf = 0; amf < 8; ++amf)
    rsv[amf] = *(const float4*)&rowsum[orow0 + amf * 16];
  #pragma unroll
  for (int anf = 0; anf < 4; ++anf) {
    const int n = ocol0 + anf * 16;
    const float sc = scale[n];
    const float of = offset[n];
    #pragma unroll
    for (int amf = 0; amf < 8; ++amf) {
      const int mbase = orow0 + amf * 16;
      const float4 rv = rsv[amf];
      out[(size_t)(mbase + 0) * N_DIM + n] = (acc[amf][anf][0] + of * rv.x) * sc;
      out[(size_t)(mbase + 1) * N_DIM + n] = (acc[amf][anf][1] + of * rv.y) * sc;
      out[(size_t)(mbase + 2) * N_DIM + n] = (acc[amf][anf][2] + of * rv.z) * sc;
      out[(size_t)(mbase + 3) * N_DIM + n] = (acc[amf][anf][3] + of * rv.w) * sc;
    }
  }
}

// ---------------- fallback (ws too small): exact f32 tiled GEMM ----------------
__global__ __launch_bounds__(256) void fallback_gemm(const float* __restrict__ x,
                                                     const int* __restrict__ w,
                                                     const float* __restrict__ scale,
                                                     const float* __restrict__ offset,
                                                     float* __restrict__ out) {
  __shared__ float xs[32][33];
  __shared__ float bs[32][33];
  const int bm = blockIdx.y * 32, bn = blockIdx.x * 32;
  const int t = threadIdx.x;
  const int tm = t >> 5, tn = t & 31;
  float acc[4] = {0.f, 0.f, 0.f, 0.f};
  for (int k0 = 0; k0 < K_DIM; k0 += 32) {
    #pragma unroll
    for (int i = 0; i < 4; ++i) {
      int idx = t + i * 256; int r = idx >> 5, c = idx & 31;
      xs[r][c] = x[(size_t)(bm + r) * K_DIM + k0 + c];
      bs[r][c] = ((float)w[(size_t)(k0 + r) * N_DIM + bn + c] + offset[bn + c]) * scale[bn + c];
    }
    __syncthreads();
    #pragma unroll 8
    for (int kk = 0; kk < 32; ++kk) {
      float wv = bs[kk][tn];
      #pragma unroll
      for (int i = 0; i < 4; ++i) acc[i] += xs[tm + 8 * i][kk] * wv;
    }
    __syncthreads();
  }
  #pragma unroll
  for (int i = 0; i < 4; ++i)
    out[(size_t)(bm + tm + 8 * i) * N_DIM + bn + tn] = acc[i];
}

extern "C" void kernel_launch(void* const* d_in, const int* in_sizes, int n_in,
                              void* d_out, int out_size, void* d_ws, size_t ws_size,
                              hipStream_t stream) {
  const float* x      = (const float*)d_in[0];
  const int*   w      = (const int*)d_in[1];
  const float* scale  = (const float*)d_in[2];
  const float* offset = (const float*)d_in[3];
  float* out = (float*)d_out;

  const size_t xb_bytes = (size_t)M_DIM * K_DIM * 2;
  const size_t wt_bytes = (size_t)N_DIM * K_DIM * 2;
  const size_t rs_bytes = (size_t)M_DIM * 4;

  if (ws_size >= xb_bytes + wt_bytes + rs_bytes) {
    short* xb = (short*)d_ws;
    short* wt = (short*)((char*)d_ws + xb_bytes);
    float* rowsum = (float*)((char*)d_ws + xb_bytes + wt_bytes);
    convert_x_kernel<<<M_DIM, 256, 0, stream>>>(x, xb, rowsum);
    convert_w_kernel<<<dim3(K_DIM / 64, N_DIM / 64), 256, 0, stream>>>(w, wt);
    gemm_kernel<<<GRID_MN, 512, 0, stream>>>(xb, wt, scale, offset, rowsum, out);
  } else {
    fallback_gemm<<<dim3(N_DIM / 32, M_DIM / 32), 256, 0, stream>>>(x, w, scale, offset, out);
  }
}